// Round 8
// baseline (395.736 us; speedup 1.0000x reference)
//
#include <hip/hip_runtime.h>

#define HW 4096
#define NE 1024
#define LOSS_OFF 16777216
#define IDX_OFF  16777218
#define KPB 528           // zt row pitch: 132 dwords = 4 mod 32 banks -> 2-way (free)
#define MARGIN 0.08f
#define RB 8              // refine rows per block

typedef __attribute__((ext_vector_type(8))) _Float16 half8v;
typedef __attribute__((ext_vector_type(4))) float float4v;

// ws layout (bytes): [0] int flag_count; [64..) int flaglist[65536];
// [262208..) float cnorm[1024]; [266304..) ushort cbh[1024*256]; [790592..) float part[4096]
#define WS_LIST_OFF   64
#define WS_CNORM_OFF  262208
#define WS_CBH_OFF    266304
#define WS_PART_OFF   790592

__device__ __forceinline__ unsigned short f16rne(float f) {
    _Float16 h = (_Float16)f;            // v_cvt_f16_f32, RNE
    return __builtin_bit_cast(unsigned short, h);
}

__device__ __forceinline__ unsigned f16pk(float a, float b) {
    auto h = __builtin_amdgcn_cvt_pkrtz(a, b);   // v_cvt_pkrtz_f16_f32
    return __builtin_bit_cast(unsigned, h);
}

// ---------------- k0: codebook half-norms + fp16 conversion + counter zero ----------------
__global__ __launch_bounds__(256) void k0_prep(const float* __restrict__ cb,
                                               float* __restrict__ cnorm,
                                               unsigned short* __restrict__ cbh,
                                               int* __restrict__ flagcnt) {
    int e = blockIdx.x * 256 + threadIdx.x;   // grid 4 x 256 = 1024
    if (e == 0) *flagcnt = 0;
    const float4* row = (const float4*)(cb + (size_t)e * 256);
    unsigned short* dst = cbh + (size_t)e * 256;
    float s = 0.f;
#pragma unroll 8
    for (int i = 0; i < 64; ++i) {
        float4 v = row[i];
        s += v.x * v.x + v.y * v.y + v.z * v.z + v.w * v.w;
        unsigned p0 = (unsigned)f16rne(v.x) | ((unsigned)f16rne(v.y) << 16);
        unsigned p1 = (unsigned)f16rne(v.z) | ((unsigned)f16rne(v.w) << 16);
        *(uint2*)(dst + i * 4) = make_uint2(p0, p1);
    }
    cnorm[e] = 0.5f * s;
}

// ---------------- k1: fp16 MFMA distance + argmin(best1,best2) + flagging ----------------
// Block: 64 rows x 1024 entries, 4 waves (wy: 32-row half, wx: 32-entry half of chunk).
// zt resident in LDS (padded rows). B-frags loaded DIRECTLY from L2-resident fp16
// codebook with immediate offsets. No barriers, no reg arrays across barriers.
__global__ __launch_bounds__(256, 4) void k1_mfma(const float* __restrict__ z,
                                                  const unsigned short* __restrict__ cbh,
                                                  const float* __restrict__ cnorm,
                                                  float* __restrict__ out_idx,
                                                  int* __restrict__ flagcnt,
                                                  int* __restrict__ flaglist) {
    __shared__ __align__(16) char smem[35328];
    char* zt = smem;                         // [64][KPB]
    float* cand1 = (float*)(smem + 33792);   // [64][2]
    int*   candi = (int*)  (smem + 34304);
    float* cand2 = (float*)(smem + 34816);

    const int tid = threadIdx.x;
    const int lane = tid & 63, w = tid >> 6;
    const int wx = w & 1, wy = w >> 1;
    const int lr = lane & 15, lg = lane >> 4;

    const int n0 = blockIdx.x * 64;
    const int hw0 = n0 & 4095;
    const float* zb = z + (size_t)(n0 >> 12) * (256 * HW);

    // ---- stage z tile transposed: [row][k] fp16 (padded rows, conflict-benign) ----
    {
        const int row = tid & 63, kg8 = tid >> 6;
#pragma unroll
        for (int it = 0; it < 8; ++it) {
            int kb = (kg8 + it * 4) * 8;
            float v[8];
#pragma unroll
            for (int q = 0; q < 8; ++q) v[q] = zb[(size_t)(kb + q) * HW + hw0 + row];
            unsigned pk[4];
#pragma unroll
            for (int q = 0; q < 4; ++q) pk[q] = f16pk(v[2*q], v[2*q+1]);
            *(int4*)(zt + row * KPB + kb * 2) = make_int4(pk[0], pk[1], pk[2], pk[3]);
        }
    }
    __syncthreads();

    // per-thread pointers (all inner-loop offsets are immediates)
    const char* bp0 = (const char*)cbh + (size_t)(32*wx + lr) * 512 + 16*lg;  // jx=0
    const char* bp1 = bp0 + 8192;                                             // jx=1
    const float* cnp = cnorm + 32*wx + lr;
    const char* ap0 = zt + (32*wy + lr) * KPB + 16*lg;
    const char* ap1 = ap0 + 16 * KPB;

    float b1[8], b2[8]; int bi[8];
#pragma unroll
    for (int i = 0; i < 8; ++i) { b1[i] = 1e30f; b2[i] = 1e30f; bi[i] = 0; }

    for (int c = 0; c < 16; ++c) {
        float4v acc00 = {0.f,0.f,0.f,0.f}, acc01 = acc00, acc10 = acc00, acc11 = acc00;
#pragma unroll
        for (int ks = 0; ks < 8; ++ks) {
            half8v B0 = *(const half8v*)(bp0 + ks * 64);
            half8v B1 = *(const half8v*)(bp1 + ks * 64);
            half8v A0 = *(const half8v*)(ap0 + ks * 64);
            half8v A1 = *(const half8v*)(ap1 + ks * 64);
            acc00 = __builtin_amdgcn_mfma_f32_16x16x32_f16(A0, B0, acc00, 0, 0, 0);
            acc10 = __builtin_amdgcn_mfma_f32_16x16x32_f16(A1, B0, acc10, 0, 0, 0);
            acc01 = __builtin_amdgcn_mfma_f32_16x16x32_f16(A0, B1, acc01, 0, 0, 0);
            acc11 = __builtin_amdgcn_mfma_f32_16x16x32_f16(A1, B1, acc11, 0, 0, 0);
        }

        // fold: jx=0 (e0) before jx=1 (e0+16) -> entries strictly ascending per slot
        {
            const int e0 = c * 64 + 32 * wx + lr;
            const float cn0 = cnp[0], cn1 = cnp[16];
#pragma unroll
            for (int r = 0; r < 4; ++r) {
                float s = cn0 - acc00[r];
                if (s < b1[r]) { b2[r] = b1[r]; b1[r] = s; bi[r] = e0; }
                else if (s < b2[r]) b2[r] = s;
                float t = cn0 - acc10[r];
                if (t < b1[4+r]) { b2[4+r] = b1[4+r]; b1[4+r] = t; bi[4+r] = e0; }
                else if (t < b2[4+r]) b2[4+r] = t;
            }
#pragma unroll
            for (int r = 0; r < 4; ++r) {
                float s = cn1 - acc01[r];
                if (s < b1[r]) { b2[r] = b1[r]; b1[r] = s; bi[r] = e0 + 16; }
                else if (s < b2[r]) b2[r] = s;
                float t = cn1 - acc11[r];
                if (t < b1[4+r]) { b2[4+r] = b1[4+r]; b1[4+r] = t; bi[4+r] = e0 + 16; }
                else if (t < b2[4+r]) b2[4+r] = t;
            }
        }
        bp0 += 32768; bp1 += 32768; cnp += 64;
    }

    // ---- cross-lane argmin over the 16-lane entry dimension (lr) ----
#pragma unroll
    for (int m = 1; m <= 8; m <<= 1) {
#pragma unroll
        for (int s = 0; s < 8; ++s) {
            float o1 = __shfl_xor(b1[s], m, 64);
            float o2 = __shfl_xor(b2[s], m, 64);
            int   oi = __shfl_xor(bi[s], m, 64);
            float m2 = fminf(fmaxf(b1[s], o1), fminf(b2[s], o2));
            if (o1 < b1[s] || (o1 == b1[s] && oi < bi[s])) { b1[s] = o1; bi[s] = oi; }
            b2[s] = m2;
        }
    }
    if (lr == 0) {
#pragma unroll
        for (int mi = 0; mi < 2; ++mi)
#pragma unroll
            for (int r = 0; r < 4; ++r) {
                int row = 32 * wy + 16 * mi + 4 * lg + r;
                cand1[row * 2 + wx] = b1[mi * 4 + r];
                cand2[row * 2 + wx] = b2[mi * 4 + r];
                candi[row * 2 + wx] = bi[mi * 4 + r];
            }
    }
    __syncthreads();
    if (tid < 64) {
        float s1a = cand1[tid * 2], s1b = cand1[tid * 2 + 1];
        int   ia = candi[tid * 2],  ib = candi[tid * 2 + 1];
        float s2 = fminf(fminf(cand2[tid * 2], cand2[tid * 2 + 1]), fmaxf(s1a, s1b));
        float s1; int iw;
        if (s1b < s1a || (s1b == s1a && ib < ia)) { s1 = s1b; iw = ib; }
        else { s1 = s1a; iw = ia; }
        out_idx[n0 + tid] = (float)iw;
        if (s2 - s1 < MARGIN) {
            int p = atomicAdd(flagcnt, 1);
            flaglist[p] = n0 + tid;
        }
    }
}

// ---------------- k1b: exact fp32 re-argmin, 8 flagged rows per block ----------------
__global__ __launch_bounds__(256) void k1b_refine(const float* __restrict__ z,
                                                  const float* __restrict__ cb,
                                                  const float* __restrict__ cnorm,
                                                  const int* __restrict__ flagcnt,
                                                  const int* __restrict__ flaglist,
                                                  float* __restrict__ out_idx) {
    __shared__ float zr[RB][260];
    __shared__ int   rows[RB];
    __shared__ float wb[4][RB];
    __shared__ int   wi[4][RB];
    const int tid = threadIdx.x;
    const int lane = tid & 63, w = tid >> 6;
    const int count = *flagcnt;
    for (int base = blockIdx.x * RB; base < count; base += gridDim.x * RB) {
        const int nr = min(RB, count - base);
        __syncthreads();   // protect zr/rows/wb from previous iteration
        if (tid < nr) rows[tid] = flaglist[base + tid];
        __syncthreads();
        for (int r = 0; r < nr; ++r) {
            const int n = rows[r];
            zr[r][tid] = z[((size_t)(n >> 12) * 256 + tid) * HW + (n & 4095)];
        }
        __syncthreads();

        float best[RB]; int bidx[RB];
#pragma unroll
        for (int r = 0; r < RB; ++r) { best[r] = 1e30f; bidx[r] = 0; }

#pragma unroll
        for (int p = 0; p < 4; ++p) {
            const int e = p * 256 + tid;
            const float4* cv = (const float4*)(cb + (size_t)e * 256);
            float d0[RB], d1[RB], d2[RB], d3[RB];
#pragma unroll
            for (int r = 0; r < RB; ++r) { d0[r] = d1[r] = d2[r] = d3[r] = 0.f; }
#pragma unroll 8
            for (int q = 0; q < 64; ++q) {
                float4 c = cv[q];
#pragma unroll
                for (int r = 0; r < RB; ++r) {
                    float4 zv = *(const float4*)(&zr[r][q * 4]);   // broadcast
                    d0[r] = fmaf(zv.x, c.x, d0[r]);
                    d1[r] = fmaf(zv.y, c.y, d1[r]);
                    d2[r] = fmaf(zv.z, c.z, d2[r]);
                    d3[r] = fmaf(zv.w, c.w, d3[r]);
                }
            }
            const float cn = cnorm[e];
#pragma unroll
            for (int r = 0; r < RB; ++r) {
                float s = cn - ((d0[r] + d1[r]) + (d2[r] + d3[r]));
                if (s < best[r]) { best[r] = s; bidx[r] = e; }
            }
        }
#pragma unroll
        for (int m = 1; m <= 32; m <<= 1) {
#pragma unroll
            for (int r = 0; r < RB; ++r) {
                float ob = __shfl_xor(best[r], m, 64);
                int   oi = __shfl_xor(bidx[r], m, 64);
                if (ob < best[r] || (ob == best[r] && oi < bidx[r])) { best[r] = ob; bidx[r] = oi; }
            }
        }
        if (lane == 0) {
#pragma unroll
            for (int r = 0; r < RB; ++r) { wb[w][r] = best[r]; wi[w][r] = bidx[r]; }
        }
        __syncthreads();
        if (tid < nr) {
            float bb = wb[0][tid]; int ii = wi[0][tid];
#pragma unroll
            for (int q = 1; q < 4; ++q)
                if (wb[q][tid] < bb || (wb[q][tid] == bb && wi[q][tid] < ii)) { bb = wb[q][tid]; ii = wi[q][tid]; }
            out_idx[rows[tid]] = (float)ii;
        }
        __syncthreads();
    }
}

// ---------------- k2: gather z_q + fused loss partials ----------------
__global__ __launch_bounds__(256) void k2_scatter(const float* __restrict__ z,
                                                  const float* __restrict__ cb,
                                                  const float* __restrict__ idxf,
                                                  float* __restrict__ zq,
                                                  float* __restrict__ part) {
    __shared__ float ls[4];
    size_t base = (size_t)blockIdx.x * 256 + threadIdx.x;   // grid 4096
    float lsum = 0.f;
#pragma unroll
    for (int it = 0; it < 16; ++it) {
        size_t flat = base + (size_t)it * 1048576;
        int c = (int)((flat >> 12) & 255);
        int n = (int)(((flat >> 20) << 12) | (flat & 4095));
        int e = (int)idxf[n];
        float q = cb[e * 256 + c];
        zq[flat] = q;
        float d = q - z[flat];
        lsum += d * d;
    }
#pragma unroll
    for (int m = 32; m >= 1; m >>= 1) lsum += __shfl_down(lsum, m, 64);
    int lane = threadIdx.x & 63, w = threadIdx.x >> 6;
    if (lane == 0) ls[w] = lsum;
    __syncthreads();
    if (threadIdx.x == 0) part[blockIdx.x] = ls[0] + ls[1] + ls[2] + ls[3];
}

// ---------------- k3: final loss reduce + constants ----------------
__global__ __launch_bounds__(256) void k3_final(const float* __restrict__ part,
                                                float* __restrict__ dout) {
    __shared__ float ls[4];
    float s = 0.f;
#pragma unroll
    for (int it = 0; it < 16; ++it) s += part[threadIdx.x + it * 256];
#pragma unroll
    for (int m = 32; m >= 1; m >>= 1) s += __shfl_down(s, m, 64);
    int lane = threadIdx.x & 63, w = threadIdx.x >> 6;
    if (lane == 0) ls[w] = s;
    __syncthreads();
    if (threadIdx.x == 0) {
        float total = ls[0] + ls[1] + ls[2] + ls[3];
        dout[LOSS_OFF]     = total / 16777216.0f;
        dout[LOSS_OFF + 1] = 0.0f;
    }
}

extern "C" void kernel_launch(void* const* d_in, const int* in_sizes, int n_in,
                              void* d_out, int out_size, void* d_ws, size_t ws_size,
                              hipStream_t stream) {
    const float* z  = (const float*)d_in[0];
    const float* cb = (const float*)d_in[1];
    float* out = (float*)d_out;
    char* ws = (char*)d_ws;

    int*            flagcnt  = (int*)ws;
    int*            flaglist = (int*)(ws + WS_LIST_OFF);
    float*          cnorm    = (float*)(ws + WS_CNORM_OFF);
    unsigned short* cbh      = (unsigned short*)(ws + WS_CBH_OFF);
    float*          part     = (float*)(ws + WS_PART_OFF);

    hipLaunchKernelGGL(k0_prep,   dim3(4),    dim3(256), 0, stream, cb, cnorm, cbh, flagcnt);
    hipLaunchKernelGGL(k1_mfma,   dim3(1024), dim3(256), 0, stream,
                       z, cbh, cnorm, out + IDX_OFF, flagcnt, flaglist);
    hipLaunchKernelGGL(k1b_refine, dim3(1024), dim3(256), 0, stream,
                       z, cb, cnorm, flagcnt, flaglist, out + IDX_OFF);
    hipLaunchKernelGGL(k2_scatter, dim3(4096), dim3(256), 0, stream,
                       z, cb, out + IDX_OFF, out, part);
    hipLaunchKernelGGL(k3_final,  dim3(1),    dim3(256), 0, stream, part, out);
}

// Round 9
// 198.315 us; speedup vs baseline: 1.9955x; 1.9955x over previous
//
#include <hip/hip_runtime.h>

#define HW 4096
#define NE 1024
#define LOSS_OFF 16777216
#define IDX_OFF  16777218
#define MARGIN 0.08f
#define RB 8              // refine rows per block

typedef __attribute__((ext_vector_type(8))) _Float16 half8v;
typedef __attribute__((ext_vector_type(4))) float float4v;

// ws layout (bytes): [0] int flag_count; [64..) int flaglist[65536];
// [262208..) float cnorm[1024]; [266304..) ushort cbh[1024*256]; [790592..) float part[4096]
#define WS_LIST_OFF   64
#define WS_CNORM_OFF  262208
#define WS_CBH_OFF    266304
#define WS_PART_OFF   790592

__device__ __forceinline__ unsigned short f16rne(float f) {
    _Float16 h = (_Float16)f;            // v_cvt_f16_f32, RNE
    return __builtin_bit_cast(unsigned short, h);
}

__device__ __forceinline__ unsigned f16pk(float a, float b) {
    auto h = __builtin_amdgcn_cvt_pkrtz(a, b);   // v_cvt_pkrtz_f16_f32
    return __builtin_bit_cast(unsigned, h);
}

// async global->LDS, 16B per lane; lds base must be wave-uniform (HW adds lane*16)
__device__ __forceinline__ void stage16(const void* g, void* l) {
    __builtin_amdgcn_global_load_lds(
        (const __attribute__((address_space(1))) unsigned*)g,
        (__attribute__((address_space(3))) unsigned*)l, 16, 0, 0);
}

// ---------------- k0: codebook half-norms + fp16 conversion + counter zero ----------------
__global__ __launch_bounds__(256) void k0_prep(const float* __restrict__ cb,
                                               float* __restrict__ cnorm,
                                               unsigned short* __restrict__ cbh,
                                               int* __restrict__ flagcnt) {
    int e = blockIdx.x * 256 + threadIdx.x;   // grid 4 x 256 = 1024
    if (e == 0) *flagcnt = 0;
    const float4* row = (const float4*)(cb + (size_t)e * 256);
    unsigned short* dst = cbh + (size_t)e * 256;
    float s = 0.f;
#pragma unroll 8
    for (int i = 0; i < 64; ++i) {
        float4 v = row[i];
        s += v.x * v.x + v.y * v.y + v.z * v.z + v.w * v.w;
        unsigned p0 = (unsigned)f16rne(v.x) | ((unsigned)f16rne(v.y) << 16);
        unsigned p1 = (unsigned)f16rne(v.z) | ((unsigned)f16rne(v.w) << 16);
        *(uint2*)(dst + i * 4) = make_uint2(p0, p1);
    }
    cnorm[e] = 0.5f * s;
}

// ---------------- k1: fp16 MFMA distance + argmin(best1,best2) + flagging ----------------
// Block: 64 rows x 1024 entries, 4 waves (wy = 32-row half, wx = 16-entry half of a
// 32-entry chunk). 32 chunks of 16KB staged async (global_load_lds) into a 2x16KB
// double buffer; z-tile transposes through the same 32KB (dead after A-frag load).
// XOR-swizzle key (row&15)<<4 on both stage-source and LDS reads.
__global__ __launch_bounds__(256, 3) void k1_mfma(const float* __restrict__ z,
                                                  const unsigned short* __restrict__ cbh,
                                                  const float* __restrict__ cnorm,
                                                  float* __restrict__ out_idx,
                                                  int* __restrict__ flagcnt,
                                                  int* __restrict__ flaglist) {
    __shared__ __align__(16) char smem[34304];
    char* bufs = smem;                       // 2 x 16384 (zt aliases [0..32768))
    float* cand1 = (float*)(smem + 32768);   // [64][2]
    int*   candi = (int*)  (smem + 33280);
    float* cand2 = (float*)(smem + 33792);

    const int tid = threadIdx.x;
    const int lane = tid & 63, w = tid >> 6;
    const int wx = w & 1, wy = w >> 1;
    const int lr = lane & 15, lg = lane >> 4;
    const unsigned bswz = (unsigned)(lr << 4);   // (row&15)<<4 with row%16 == lr

    const int n0 = blockIdx.x * 64;
    const int hw0 = n0 & 4095;
    const float* zb = z + (size_t)(n0 >> 12) * (256 * HW);
    const char* cbh_b = (const char*)cbh;

    // ---- stage z tile transposed [row][k] fp16 into smem[0..32768) (swizzled) ----
    {
        const int row = tid & 63, kg8 = tid >> 6;
        const unsigned zswz = (unsigned)((row & 15) << 4);
#pragma unroll
        for (int it = 0; it < 8; ++it) {
            int kb = (kg8 + it * 4) * 8;
            float v[8];
#pragma unroll
            for (int q = 0; q < 8; ++q) v[q] = zb[(size_t)(kb + q) * HW + hw0 + row];
            unsigned pk[4];
#pragma unroll
            for (int q = 0; q < 4; ++q) pk[q] = f16pk(v[2*q], v[2*q+1]);
            unsigned scol = (unsigned)(kb * 2) ^ zswz;
            *(int4*)(smem + row * 512 + scol) = make_int4(pk[0], pk[1], pk[2], pk[3]);
        }
    }
    __syncthreads();

    // ---- A-frags: this wave's 32 rows, full K (64 VGPR) ----
    half8v A[2][8];
#pragma unroll
    for (int mi = 0; mi < 2; ++mi)
#pragma unroll
        for (int ks = 0; ks < 8; ++ks)
            A[mi][ks] = *(const half8v*)(smem + (32*wy + 16*mi + lr) * 512
                                              + ((unsigned)(64*ks + 16*lg) ^ bswz));
    __syncthreads();   // zt dead; buffers may be staged over it

    // ---- staging constants: instr i covers entries 2*(w*4+i), +1 of the chunk ----
    const int i0 = w * 4;
    const int elo_half = lane >> 5;                 // 0/1
    const unsigned col0 = (unsigned)((lane & 31) * 16);

    // stage chunk 0 -> buf0
#pragma unroll
    for (int i = 0; i < 4; ++i) {
        int e_loc = 2 * (i0 + i) + elo_half;
        unsigned col = col0 ^ (unsigned)((e_loc & 15) << 4);
        stage16(cbh_b + (size_t)e_loc * 512 + col, bufs + (i0 + i) * 1024);
    }
    __syncthreads();

    const float* cnp = cnorm + 16 * wx + lr;
    float b1[8], b2[8]; int bi[8];
#pragma unroll
    for (int i = 0; i < 8; ++i) { b1[i] = 1e30f; b2[i] = 1e30f; bi[i] = 0; }

    for (int c = 0; c < 32; ++c) {
        // issue next chunk's async stage FIRST (overlaps with compute below)
        if (c < 31) {
            char* nb = bufs + ((c + 1) & 1) * 16384;
            const size_t ebase = (size_t)(c + 1) * 32;
#pragma unroll
            for (int i = 0; i < 4; ++i) {
                int e_loc = 2 * (i0 + i) + elo_half;
                unsigned col = col0 ^ (unsigned)((e_loc & 15) << 4);
                stage16(cbh_b + (ebase + e_loc) * 512 + col, nb + (i0 + i) * 1024);
            }
        }

        const char* bp = bufs + (c & 1) * 16384 + (16 * wx + lr) * 512;
        float4v a0 = {0.f,0.f,0.f,0.f}, a1 = a0;
#pragma unroll
        for (int ks = 0; ks < 8; ++ks) {
            half8v B = *(const half8v*)(bp + ((unsigned)(64*ks + 16*lg) ^ bswz));
            a0 = __builtin_amdgcn_mfma_f32_16x16x32_f16(A[0][ks], B, a0, 0, 0, 0);
            a1 = __builtin_amdgcn_mfma_f32_16x16x32_f16(A[1][ks], B, a1, 0, 0, 0);
        }

        // fold (entries strictly ascend with c -> strict < keeps smallest index)
        const float cn = cnp[c * 32];
        const int e = c * 32 + 16 * wx + lr;
#pragma unroll
        for (int r = 0; r < 4; ++r) {
            float s0 = cn - a0[r];
            b2[r] = fminf(b2[r], fmaxf(b1[r], s0));          // med3 clamp idiom
            if (s0 < b1[r]) { b1[r] = s0; bi[r] = e; }
            float s1 = cn - a1[r];
            b2[4+r] = fminf(b2[4+r], fmaxf(b1[4+r], s1));
            if (s1 < b1[4+r]) { b1[4+r] = s1; bi[4+r] = e; }
        }

        __syncthreads();   // next buffer staged + all reads of bp done
    }

    // ---- cross-lane argmin over the 16-lane entry dimension (lr) ----
#pragma unroll
    for (int m = 1; m <= 8; m <<= 1) {
#pragma unroll
        for (int s = 0; s < 8; ++s) {
            float o1 = __shfl_xor(b1[s], m, 64);
            float o2 = __shfl_xor(b2[s], m, 64);
            int   oi = __shfl_xor(bi[s], m, 64);
            float m2 = fminf(fmaxf(b1[s], o1), fminf(b2[s], o2));
            if (o1 < b1[s] || (o1 == b1[s] && oi < bi[s])) { b1[s] = o1; bi[s] = oi; }
            b2[s] = m2;
        }
    }
    if (lr == 0) {
#pragma unroll
        for (int mi = 0; mi < 2; ++mi)
#pragma unroll
            for (int r = 0; r < 4; ++r) {
                int row = 32 * wy + 16 * mi + 4 * lg + r;
                cand1[row * 2 + wx] = b1[mi * 4 + r];
                cand2[row * 2 + wx] = b2[mi * 4 + r];
                candi[row * 2 + wx] = bi[mi * 4 + r];
            }
    }
    __syncthreads();
    if (tid < 64) {
        float s1a = cand1[tid * 2], s1b = cand1[tid * 2 + 1];
        int   ia = candi[tid * 2],  ib = candi[tid * 2 + 1];
        float s2 = fminf(fminf(cand2[tid * 2], cand2[tid * 2 + 1]), fmaxf(s1a, s1b));
        float s1; int iw;
        if (s1b < s1a || (s1b == s1a && ib < ia)) { s1 = s1b; iw = ib; }
        else { s1 = s1a; iw = ia; }
        out_idx[n0 + tid] = (float)iw;
        if (s2 - s1 < MARGIN) {
            int p = atomicAdd(flagcnt, 1);
            flaglist[p] = n0 + tid;
        }
    }
}

// ---------------- k1b: exact fp32 re-argmin, 8 flagged rows per block ----------------
__global__ __launch_bounds__(256) void k1b_refine(const float* __restrict__ z,
                                                  const float* __restrict__ cb,
                                                  const float* __restrict__ cnorm,
                                                  const int* __restrict__ flagcnt,
                                                  const int* __restrict__ flaglist,
                                                  float* __restrict__ out_idx) {
    __shared__ float zr[RB][260];
    __shared__ int   rows[RB];
    __shared__ float wb[4][RB];
    __shared__ int   wi[4][RB];
    const int tid = threadIdx.x;
    const int lane = tid & 63, w = tid >> 6;
    const int count = *flagcnt;
    for (int base = blockIdx.x * RB; base < count; base += gridDim.x * RB) {
        const int nr = min(RB, count - base);
        __syncthreads();
        if (tid < nr) rows[tid] = flaglist[base + tid];
        __syncthreads();
        for (int r = 0; r < nr; ++r) {
            const int n = rows[r];
            zr[r][tid] = z[((size_t)(n >> 12) * 256 + tid) * HW + (n & 4095)];
        }
        __syncthreads();

        float best[RB]; int bidx[RB];
#pragma unroll
        for (int r = 0; r < RB; ++r) { best[r] = 1e30f; bidx[r] = 0; }

#pragma unroll
        for (int p = 0; p < 4; ++p) {
            const int e = p * 256 + tid;
            const float4* cv = (const float4*)(cb + (size_t)e * 256);
            float d0[RB], d1[RB], d2[RB], d3[RB];
#pragma unroll
            for (int r = 0; r < RB; ++r) { d0[r] = d1[r] = d2[r] = d3[r] = 0.f; }
#pragma unroll 8
            for (int q = 0; q < 64; ++q) {
                float4 c = cv[q];
#pragma unroll
                for (int r = 0; r < RB; ++r) {
                    float4 zv = *(const float4*)(&zr[r][q * 4]);   // broadcast
                    d0[r] = fmaf(zv.x, c.x, d0[r]);
                    d1[r] = fmaf(zv.y, c.y, d1[r]);
                    d2[r] = fmaf(zv.z, c.z, d2[r]);
                    d3[r] = fmaf(zv.w, c.w, d3[r]);
                }
            }
            const float cn = cnorm[e];
#pragma unroll
            for (int r = 0; r < RB; ++r) {
                float s = cn - ((d0[r] + d1[r]) + (d2[r] + d3[r]));
                if (s < best[r]) { best[r] = s; bidx[r] = e; }
            }
        }
#pragma unroll
        for (int m = 1; m <= 32; m <<= 1) {
#pragma unroll
            for (int r = 0; r < RB; ++r) {
                float ob = __shfl_xor(best[r], m, 64);
                int   oi = __shfl_xor(bidx[r], m, 64);
                if (ob < best[r] || (ob == best[r] && oi < bidx[r])) { best[r] = ob; bidx[r] = oi; }
            }
        }
        if (lane == 0) {
#pragma unroll
            for (int r = 0; r < RB; ++r) { wb[w][r] = best[r]; wi[w][r] = bidx[r]; }
        }
        __syncthreads();
        if (tid < nr) {
            float bb = wb[0][tid]; int ii = wi[0][tid];
#pragma unroll
            for (int q = 1; q < 4; ++q)
                if (wb[q][tid] < bb || (wb[q][tid] == bb && wi[q][tid] < ii)) { bb = wb[q][tid]; ii = wi[q][tid]; }
            out_idx[rows[tid]] = (float)ii;
        }
        __syncthreads();
    }
}

// ---------------- k2: LDS-staged gather z_q + fused loss partials ----------------
// Block = one (b, 64-hw group): gather the 64 needed codebook rows ONCE (coalesced
// 16B row reads) into LDS, then stream z/zq fully coalesced. Stride 257 -> 2-way reads.
__global__ __launch_bounds__(256) void k2_scatter(const float* __restrict__ z,
                                                  const float* __restrict__ cb,
                                                  const float* __restrict__ idxf,
                                                  float* __restrict__ zq,
                                                  float* __restrict__ part) {
    __shared__ float cbrow[64][257];
    __shared__ int   earr[64];
    __shared__ float ls[4];
    const int tid = threadIdx.x;
    const int b = blockIdx.x >> 6;
    const int hw0 = (blockIdx.x & 63) * 64;

    if (tid < 64) earr[tid] = (int)idxf[b * 4096 + hw0 + tid];
    __syncthreads();
    {
        const int r = tid >> 2, qd = tid & 3;       // row 0..63, quarter 0..3
        const float4* src = (const float4*)(cb + (size_t)earr[r] * 256 + qd * 64);
#pragma unroll
        for (int i = 0; i < 16; ++i) {
            float4 v = src[i];
            float* d = &cbrow[r][qd * 64 + i * 4];
            d[0] = v.x; d[1] = v.y; d[2] = v.z; d[3] = v.w;
        }
    }
    __syncthreads();

    const int hw = tid & 63, cq = tid >> 6;
    const size_t zbase = ((size_t)b * 256) * 4096 + hw0 + hw;
    float lsum = 0.f;
#pragma unroll 8
    for (int pass = 0; pass < 64; ++pass) {
        const int c = pass * 4 + cq;
        const size_t flat = zbase + (size_t)c * 4096;
        float q = cbrow[hw][c];
        zq[flat] = q;
        float d = q - z[flat];
        lsum = fmaf(d, d, lsum);
    }
#pragma unroll
    for (int m = 32; m >= 1; m >>= 1) lsum += __shfl_down(lsum, m, 64);
    const int lane = tid & 63, w = tid >> 6;
    if (lane == 0) ls[w] = lsum;
    __syncthreads();
    if (tid == 0) part[blockIdx.x] = ls[0] + ls[1] + ls[2] + ls[3];
}

// ---------------- k3: final loss reduce + constants ----------------
__global__ __launch_bounds__(256) void k3_final(const float* __restrict__ part,
                                                float* __restrict__ dout) {
    __shared__ float ls[4];
    float s = 0.f;
#pragma unroll
    for (int it = 0; it < 4; ++it) s += part[threadIdx.x + it * 256];
#pragma unroll
    for (int m = 32; m >= 1; m >>= 1) s += __shfl_down(s, m, 64);
    int lane = threadIdx.x & 63, w = threadIdx.x >> 6;
    if (lane == 0) ls[w] = s;
    __syncthreads();
    if (threadIdx.x == 0) {
        float total = ls[0] + ls[1] + ls[2] + ls[3];
        dout[LOSS_OFF]     = total / 16777216.0f;
        dout[LOSS_OFF + 1] = 0.0f;
    }
}

extern "C" void kernel_launch(void* const* d_in, const int* in_sizes, int n_in,
                              void* d_out, int out_size, void* d_ws, size_t ws_size,
                              hipStream_t stream) {
    const float* z  = (const float*)d_in[0];
    const float* cb = (const float*)d_in[1];
    float* out = (float*)d_out;
    char* ws = (char*)d_ws;

    int*            flagcnt  = (int*)ws;
    int*            flaglist = (int*)(ws + WS_LIST_OFF);
    float*          cnorm    = (float*)(ws + WS_CNORM_OFF);
    unsigned short* cbh      = (unsigned short*)(ws + WS_CBH_OFF);
    float*          part     = (float*)(ws + WS_PART_OFF);

    hipLaunchKernelGGL(k0_prep,   dim3(4),    dim3(256), 0, stream, cb, cnorm, cbh, flagcnt);
    hipLaunchKernelGGL(k1_mfma,   dim3(1024), dim3(256), 0, stream,
                       z, cbh, cnorm, out + IDX_OFF, flagcnt, flaglist);
    hipLaunchKernelGGL(k1b_refine, dim3(1024), dim3(256), 0, stream,
                       z, cb, cnorm, flagcnt, flaglist, out + IDX_OFF);
    hipLaunchKernelGGL(k2_scatter, dim3(1024), dim3(256), 0, stream,
                       z, cb, out + IDX_OFF, out, part);
    hipLaunchKernelGGL(k3_final,  dim3(1),    dim3(256), 0, stream, part, out);
}

// Round 10
// 144.605 us; speedup vs baseline: 2.7367x; 1.3714x over previous
//
#include <hip/hip_runtime.h>

#define HW 4096
#define NE 1024
#define LOSS_OFF 16777216
#define IDX_OFF  16777218
#define MARGIN 0.08f

typedef __attribute__((ext_vector_type(8))) _Float16 half8v;
typedef __attribute__((ext_vector_type(4))) float float4v;

// ws layout (bytes): [0] int flag_count; [64..) int flaglist[65536];
// [262208..) float cnorm[1024]; [266304..) ushort cbh[1024*256]; [790592..) float part[4096]
#define WS_LIST_OFF   64
#define WS_CNORM_OFF  262208
#define WS_CBH_OFF    266304
#define WS_PART_OFF   790592

__device__ __forceinline__ unsigned short f16rne(float f) {
    _Float16 h = (_Float16)f;            // v_cvt_f16_f32, RNE
    return __builtin_bit_cast(unsigned short, h);
}

__device__ __forceinline__ unsigned f16pk(float a, float b) {
    auto h = __builtin_amdgcn_cvt_pkrtz(a, b);   // v_cvt_pkrtz_f16_f32
    return __builtin_bit_cast(unsigned, h);
}

// async global->LDS, 16B per lane; lds base must be wave-uniform (HW adds lane*16)
__device__ __forceinline__ void stage16(const void* g, void* l) {
    __builtin_amdgcn_global_load_lds(
        (const __attribute__((address_space(1))) unsigned*)g,
        (__attribute__((address_space(3))) unsigned*)l, 16, 0, 0);
}

// ---------------- k0: codebook half-norms + fp16 conversion + counter zero ----------------
__global__ __launch_bounds__(256) void k0_prep(const float* __restrict__ cb,
                                               float* __restrict__ cnorm,
                                               unsigned short* __restrict__ cbh,
                                               int* __restrict__ flagcnt) {
    int e = blockIdx.x * 256 + threadIdx.x;   // grid 4 x 256 = 1024
    if (e == 0) *flagcnt = 0;
    const float4* row = (const float4*)(cb + (size_t)e * 256);
    unsigned short* dst = cbh + (size_t)e * 256;
    float s = 0.f;
#pragma unroll 8
    for (int i = 0; i < 64; ++i) {
        float4 v = row[i];
        s += v.x * v.x + v.y * v.y + v.z * v.z + v.w * v.w;
        unsigned p0 = (unsigned)f16rne(v.x) | ((unsigned)f16rne(v.y) << 16);
        unsigned p1 = (unsigned)f16rne(v.z) | ((unsigned)f16rne(v.w) << 16);
        *(uint2*)(dst + i * 4) = make_uint2(p0, p1);
    }
    cnorm[e] = 0.5f * s;
}

// ---------------- k1: fp16 MFMA distance + argmin(best1,best2) + flagging ----------------
// (unchanged from round 9 — passed, left out of top-5)
__global__ __launch_bounds__(256, 3) void k1_mfma(const float* __restrict__ z,
                                                  const unsigned short* __restrict__ cbh,
                                                  const float* __restrict__ cnorm,
                                                  float* __restrict__ out_idx,
                                                  int* __restrict__ flagcnt,
                                                  int* __restrict__ flaglist) {
    __shared__ __align__(16) char smem[34304];
    char* bufs = smem;                       // 2 x 16384 (zt aliases [0..32768))
    float* cand1 = (float*)(smem + 32768);   // [64][2]
    int*   candi = (int*)  (smem + 33280);
    float* cand2 = (float*)(smem + 33792);

    const int tid = threadIdx.x;
    const int lane = tid & 63, w = tid >> 6;
    const int wx = w & 1, wy = w >> 1;
    const int lr = lane & 15, lg = lane >> 4;
    const unsigned bswz = (unsigned)(lr << 4);   // (row&15)<<4 with row%16 == lr

    const int n0 = blockIdx.x * 64;
    const int hw0 = n0 & 4095;
    const float* zb = z + (size_t)(n0 >> 12) * (256 * HW);
    const char* cbh_b = (const char*)cbh;

    // ---- stage z tile transposed [row][k] fp16 into smem[0..32768) (swizzled) ----
    {
        const int row = tid & 63, kg8 = tid >> 6;
        const unsigned zswz = (unsigned)((row & 15) << 4);
#pragma unroll
        for (int it = 0; it < 8; ++it) {
            int kb = (kg8 + it * 4) * 8;
            float v[8];
#pragma unroll
            for (int q = 0; q < 8; ++q) v[q] = zb[(size_t)(kb + q) * HW + hw0 + row];
            unsigned pk[4];
#pragma unroll
            for (int q = 0; q < 4; ++q) pk[q] = f16pk(v[2*q], v[2*q+1]);
            unsigned scol = (unsigned)(kb * 2) ^ zswz;
            *(int4*)(smem + row * 512 + scol) = make_int4(pk[0], pk[1], pk[2], pk[3]);
        }
    }
    __syncthreads();

    // ---- A-frags: this wave's 32 rows, full K (64 VGPR) ----
    half8v A[2][8];
#pragma unroll
    for (int mi = 0; mi < 2; ++mi)
#pragma unroll
        for (int ks = 0; ks < 8; ++ks)
            A[mi][ks] = *(const half8v*)(smem + (32*wy + 16*mi + lr) * 512
                                              + ((unsigned)(64*ks + 16*lg) ^ bswz));
    __syncthreads();   // zt dead; buffers may be staged over it

    // ---- staging constants: instr i covers entries 2*(w*4+i), +1 of the chunk ----
    const int i0 = w * 4;
    const int elo_half = lane >> 5;                 // 0/1
    const unsigned col0 = (unsigned)((lane & 31) * 16);

    // stage chunk 0 -> buf0
#pragma unroll
    for (int i = 0; i < 4; ++i) {
        int e_loc = 2 * (i0 + i) + elo_half;
        unsigned col = col0 ^ (unsigned)((e_loc & 15) << 4);
        stage16(cbh_b + (size_t)e_loc * 512 + col, bufs + (i0 + i) * 1024);
    }
    __syncthreads();

    const float* cnp = cnorm + 16 * wx + lr;
    float b1[8], b2[8]; int bi[8];
#pragma unroll
    for (int i = 0; i < 8; ++i) { b1[i] = 1e30f; b2[i] = 1e30f; bi[i] = 0; }

    for (int c = 0; c < 32; ++c) {
        // issue next chunk's async stage FIRST (overlaps with compute below)
        if (c < 31) {
            char* nb = bufs + ((c + 1) & 1) * 16384;
            const size_t ebase = (size_t)(c + 1) * 32;
#pragma unroll
            for (int i = 0; i < 4; ++i) {
                int e_loc = 2 * (i0 + i) + elo_half;
                unsigned col = col0 ^ (unsigned)((e_loc & 15) << 4);
                stage16(cbh_b + (ebase + e_loc) * 512 + col, nb + (i0 + i) * 1024);
            }
        }

        const char* bp = bufs + (c & 1) * 16384 + (16 * wx + lr) * 512;
        float4v a0 = {0.f,0.f,0.f,0.f}, a1 = a0;
#pragma unroll
        for (int ks = 0; ks < 8; ++ks) {
            half8v B = *(const half8v*)(bp + ((unsigned)(64*ks + 16*lg) ^ bswz));
            a0 = __builtin_amdgcn_mfma_f32_16x16x32_f16(A[0][ks], B, a0, 0, 0, 0);
            a1 = __builtin_amdgcn_mfma_f32_16x16x32_f16(A[1][ks], B, a1, 0, 0, 0);
        }

        // fold (entries strictly ascend with c -> strict < keeps smallest index)
        const float cn = cnp[c * 32];
        const int e = c * 32 + 16 * wx + lr;
#pragma unroll
        for (int r = 0; r < 4; ++r) {
            float s0 = cn - a0[r];
            b2[r] = fminf(b2[r], fmaxf(b1[r], s0));          // med3 clamp idiom
            if (s0 < b1[r]) { b1[r] = s0; bi[r] = e; }
            float s1 = cn - a1[r];
            b2[4+r] = fminf(b2[4+r], fmaxf(b1[4+r], s1));
            if (s1 < b1[4+r]) { b1[4+r] = s1; bi[4+r] = e; }
        }

        __syncthreads();   // next buffer staged + all reads of bp done
    }

    // ---- cross-lane argmin over the 16-lane entry dimension (lr) ----
#pragma unroll
    for (int m = 1; m <= 8; m <<= 1) {
#pragma unroll
        for (int s = 0; s < 8; ++s) {
            float o1 = __shfl_xor(b1[s], m, 64);
            float o2 = __shfl_xor(b2[s], m, 64);
            int   oi = __shfl_xor(bi[s], m, 64);
            float m2 = fminf(fmaxf(b1[s], o1), fminf(b2[s], o2));
            if (o1 < b1[s] || (o1 == b1[s] && oi < bi[s])) { b1[s] = o1; bi[s] = oi; }
            b2[s] = m2;
        }
    }
    if (lr == 0) {
#pragma unroll
        for (int mi = 0; mi < 2; ++mi)
#pragma unroll
            for (int r = 0; r < 4; ++r) {
                int row = 32 * wy + 16 * mi + 4 * lg + r;
                cand1[row * 2 + wx] = b1[mi * 4 + r];
                cand2[row * 2 + wx] = b2[mi * 4 + r];
                candi[row * 2 + wx] = bi[mi * 4 + r];
            }
    }
    __syncthreads();
    if (tid < 64) {
        float s1a = cand1[tid * 2], s1b = cand1[tid * 2 + 1];
        int   ia = candi[tid * 2],  ib = candi[tid * 2 + 1];
        float s2 = fminf(fminf(cand2[tid * 2], cand2[tid * 2 + 1]), fmaxf(s1a, s1b));
        float s1; int iw;
        if (s1b < s1a || (s1b == s1a && ib < ia)) { s1 = s1b; iw = ib; }
        else { s1 = s1a; iw = ia; }
        out_idx[n0 + tid] = (float)iw;
        if (s2 - s1 < MARGIN) {
            int p = atomicAdd(flagcnt, 1);
            flaglist[p] = n0 + tid;
        }
    }
}

// ---------------- k1b v5: exact fp32 re-argmin, 4 rows/block, 4-lane entry groups ----
// Group = 4 lanes co-reading one codebook row (64B fully-consumed lines). q-outer:
// z float4s read once per q from LDS and reused across all 16 entries (64 LDS
// reads/thread total). acc[16][4] statically indexed. Dot = 4 j-partials summed
// ((j0+j1)+(j2+j3)) via shfl_xor; argmin tie-break on smaller index.
__global__ __launch_bounds__(256) void k1b_refine(const float* __restrict__ z,
                                                  const float* __restrict__ cb,
                                                  const float* __restrict__ cnorm,
                                                  const int* __restrict__ flagcnt,
                                                  const int* __restrict__ flaglist,
                                                  float* __restrict__ out_idx) {
    __shared__ float zr[4][260];
    __shared__ int   rows[4];
    __shared__ float wb[4][4];
    __shared__ int   wi[4][4];
    const int tid = threadIdx.x;
    const int lane = tid & 63, w = tid >> 6;
    const int gid = tid >> 2, j = tid & 3;     // entry group 0..63, quarter 0..3
    const int count = *flagcnt;
    for (int base = blockIdx.x * 4; base < count; base += gridDim.x * 4) {
        const int nr = min(4, count - base);
        __syncthreads();   // protect zr/rows/wb from previous iteration
        if (tid < nr) rows[tid] = flaglist[base + tid];
        __syncthreads();
        for (int r = 0; r < nr; ++r) {
            const int n = rows[r];
            zr[r][tid] = z[((size_t)(n >> 12) * 256 + tid) * HW + (n & 4095)];
        }
        __syncthreads();

        float acc[16][4];
#pragma unroll
        for (int p = 0; p < 16; ++p)
#pragma unroll
            for (int r = 0; r < 4; ++r) acc[p][r] = 0.f;

        const char* cbase = (const char*)cb + (size_t)gid * 1024 + j * 16;
#pragma unroll 2
        for (int q = 0; q < 16; ++q) {
            float4 zv[4];
#pragma unroll
            for (int r = 0; r < 4; ++r) zv[r] = *(const float4*)(&zr[r][q * 16 + j * 4]);
#pragma unroll
            for (int p = 0; p < 16; ++p) {
                float4 c = *(const float4*)(cbase + (size_t)p * 65536 + q * 64);
#pragma unroll
                for (int r = 0; r < 4; ++r) {
                    float a = acc[p][r];
                    a = fmaf(zv[r].x, c.x, a);
                    a = fmaf(zv[r].y, c.y, a);
                    a = fmaf(zv[r].z, c.z, a);
                    a = fmaf(zv[r].w, c.w, a);
                    acc[p][r] = a;
                }
            }
        }

        // j-reduce each (entry,row) dot, fold into per-lane argmin (entries ascend in p)
        float best[4]; int bidx[4];
#pragma unroll
        for (int r = 0; r < 4; ++r) { best[r] = 1e30f; bidx[r] = 0; }
#pragma unroll
        for (int p = 0; p < 16; ++p) {
            const int e = p * 64 + gid;
            const float cn = cnorm[e];
#pragma unroll
            for (int r = 0; r < 4; ++r) {
                float d = acc[p][r];
                d += __shfl_xor(d, 1, 64);     // j0+j1 | j2+j3
                d += __shfl_xor(d, 2, 64);     // (j0+j1)+(j2+j3)
                float s = cn - d;
                if (s < best[r]) { best[r] = s; bidx[r] = e; }
            }
        }
        // cross-lane argmin over 64 lanes (j-duplicates share identical (val,idx))
#pragma unroll
        for (int m = 1; m <= 32; m <<= 1) {
#pragma unroll
            for (int r = 0; r < 4; ++r) {
                float ob = __shfl_xor(best[r], m, 64);
                int   oi = __shfl_xor(bidx[r], m, 64);
                if (ob < best[r] || (ob == best[r] && oi < bidx[r])) { best[r] = ob; bidx[r] = oi; }
            }
        }
        if (lane == 0) {
#pragma unroll
            for (int r = 0; r < 4; ++r) { wb[w][r] = best[r]; wi[w][r] = bidx[r]; }
        }
        __syncthreads();
        if (tid < nr) {
            float bb = wb[0][tid]; int ii = wi[0][tid];
#pragma unroll
            for (int q = 1; q < 4; ++q)
                if (wb[q][tid] < bb || (wb[q][tid] == bb && wi[q][tid] < ii)) { bb = wb[q][tid]; ii = wi[q][tid]; }
            out_idx[rows[tid]] = (float)ii;
        }
        __syncthreads();
    }
}

// ---------------- k2: LDS-staged gather z_q + fused loss partials ----------------
__global__ __launch_bounds__(256) void k2_scatter(const float* __restrict__ z,
                                                  const float* __restrict__ cb,
                                                  const float* __restrict__ idxf,
                                                  float* __restrict__ zq,
                                                  float* __restrict__ part) {
    __shared__ float cbrow[64][257];
    __shared__ int   earr[64];
    __shared__ float ls[4];
    const int tid = threadIdx.x;
    const int b = blockIdx.x >> 6;
    const int hw0 = (blockIdx.x & 63) * 64;

    if (tid < 64) earr[tid] = (int)idxf[b * 4096 + hw0 + tid];
    __syncthreads();
    {
        const int r = tid >> 2, qd = tid & 3;       // row 0..63, quarter 0..3
        const float4* src = (const float4*)(cb + (size_t)earr[r] * 256 + qd * 64);
#pragma unroll
        for (int i = 0; i < 16; ++i) {
            float4 v = src[i];
            float* d = &cbrow[r][qd * 64 + i * 4];
            d[0] = v.x; d[1] = v.y; d[2] = v.z; d[3] = v.w;
        }
    }
    __syncthreads();

    const int hw = tid & 63, cq = tid >> 6;
    const size_t zbase = ((size_t)b * 256) * 4096 + hw0 + hw;
    float lsum = 0.f;
#pragma unroll 8
    for (int pass = 0; pass < 64; ++pass) {
        const int c = pass * 4 + cq;
        const size_t flat = zbase + (size_t)c * 4096;
        float q = cbrow[hw][c];
        zq[flat] = q;
        float d = q - z[flat];
        lsum = fmaf(d, d, lsum);
    }
#pragma unroll
    for (int m = 32; m >= 1; m >>= 1) lsum += __shfl_down(lsum, m, 64);
    const int lane = tid & 63, w = tid >> 6;
    if (lane == 0) ls[w] = lsum;
    __syncthreads();
    if (tid == 0) part[blockIdx.x] = ls[0] + ls[1] + ls[2] + ls[3];
}

// ---------------- k3: final loss reduce + constants ----------------
__global__ __launch_bounds__(256) void k3_final(const float* __restrict__ part,
                                                float* __restrict__ dout) {
    __shared__ float ls[4];
    float s = 0.f;
#pragma unroll
    for (int it = 0; it < 4; ++it) s += part[threadIdx.x + it * 256];
#pragma unroll
    for (int m = 32; m >= 1; m >>= 1) s += __shfl_down(s, m, 64);
    int lane = threadIdx.x & 63, w = threadIdx.x >> 6;
    if (lane == 0) ls[w] = s;
    __syncthreads();
    if (threadIdx.x == 0) {
        float total = ls[0] + ls[1] + ls[2] + ls[3];
        dout[LOSS_OFF]     = total / 16777216.0f;
        dout[LOSS_OFF + 1] = 0.0f;
    }
}

extern "C" void kernel_launch(void* const* d_in, const int* in_sizes, int n_in,
                              void* d_out, int out_size, void* d_ws, size_t ws_size,
                              hipStream_t stream) {
    const float* z  = (const float*)d_in[0];
    const float* cb = (const float*)d_in[1];
    float* out = (float*)d_out;
    char* ws = (char*)d_ws;

    int*            flagcnt  = (int*)ws;
    int*            flaglist = (int*)(ws + WS_LIST_OFF);
    float*          cnorm    = (float*)(ws + WS_CNORM_OFF);
    unsigned short* cbh      = (unsigned short*)(ws + WS_CBH_OFF);
    float*          part     = (float*)(ws + WS_PART_OFF);

    hipLaunchKernelGGL(k0_prep,   dim3(4),    dim3(256), 0, stream, cb, cnorm, cbh, flagcnt);
    hipLaunchKernelGGL(k1_mfma,   dim3(1024), dim3(256), 0, stream,
                       z, cbh, cnorm, out + IDX_OFF, flagcnt, flaglist);
    hipLaunchKernelGGL(k1b_refine, dim3(2048), dim3(256), 0, stream,
                       z, cb, cnorm, flagcnt, flaglist, out + IDX_OFF);
    hipLaunchKernelGGL(k2_scatter, dim3(1024), dim3(256), 0, stream,
                       z, cb, out + IDX_OFF, out, part);
    hipLaunchKernelGGL(k3_final,  dim3(1),    dim3(256), 0, stream, part, out);
}

// Round 11
// 135.594 us; speedup vs baseline: 2.9185x; 1.0665x over previous
//
#include <hip/hip_runtime.h>

#define HW 4096
#define NE 1024
#define LOSS_OFF 16777216
#define IDX_OFF  16777218
#define MARGIN 0.08f

typedef __attribute__((ext_vector_type(8))) _Float16 half8v;
typedef __attribute__((ext_vector_type(4))) float float4v;

// ws layout (bytes): [0] int flag_count; [64..) int flaglist[65536];
// [262208..) float cnorm[1024]; [266304..) ushort cbh[1024*256]; [790592..) float part[4096]
#define WS_LIST_OFF   64
#define WS_CNORM_OFF  262208
#define WS_CBH_OFF    266304
#define WS_PART_OFF   790592

__device__ __forceinline__ unsigned short f16rne(float f) {
    _Float16 h = (_Float16)f;            // v_cvt_f16_f32, RNE
    return __builtin_bit_cast(unsigned short, h);
}

__device__ __forceinline__ unsigned f16pk(float a, float b) {
    auto h = __builtin_amdgcn_cvt_pkrtz(a, b);   // v_cvt_pkrtz_f16_f32
    return __builtin_bit_cast(unsigned, h);
}

// async global->LDS, 16B per lane; lds base must be wave-uniform (HW adds lane*16)
__device__ __forceinline__ void stage16(const void* g, void* l) {
    __builtin_amdgcn_global_load_lds(
        (const __attribute__((address_space(1))) unsigned*)g,
        (__attribute__((address_space(3))) unsigned*)l, 16, 0, 0);
}

// ---------------- k0: codebook half-norms + fp16 conversion + counter zero ----------------
// grid 16 x 256: 4 threads per entry (quarter rows), 4-lane shfl reduce for the norm.
__global__ __launch_bounds__(256) void k0_prep(const float* __restrict__ cb,
                                               float* __restrict__ cnorm,
                                               unsigned short* __restrict__ cbh,
                                               int* __restrict__ flagcnt) {
    const int tid = threadIdx.x;
    if (blockIdx.x == 0 && tid == 0) *flagcnt = 0;
    const int e = blockIdx.x * 64 + (tid >> 2);
    const int j = tid & 3;
    const float4* src = (const float4*)(cb + (size_t)e * 256 + j * 64);
    unsigned short* dst = cbh + (size_t)e * 256 + j * 64;
    float s = 0.f;
#pragma unroll
    for (int i = 0; i < 16; ++i) {
        float4 v = src[i];
        s += v.x * v.x + v.y * v.y + v.z * v.z + v.w * v.w;
        unsigned p0 = (unsigned)f16rne(v.x) | ((unsigned)f16rne(v.y) << 16);
        unsigned p1 = (unsigned)f16rne(v.z) | ((unsigned)f16rne(v.w) << 16);
        *(uint2*)(dst + i * 4) = make_uint2(p0, p1);
    }
    s += __shfl_xor(s, 1, 64);
    s += __shfl_xor(s, 2, 64);
    if (j == 0) cnorm[e] = 0.5f * s;
}

// ---------------- k1: fp16 MFMA distance + argmin(best1,best2) + flagging ----------------
// Block: 64 rows x 1024 entries, 4 waves. Wave (wy,wx) owns rows 32*wy.. and the
// PRIVATE entry range wx*512.. : it stages its own 16-entry (8KB) chunks into its
// own double buffer via global_load_lds and paces itself with counted s_waitcnt
// vmcnt(8) — ZERO __syncthreads in the main loop (T4, legally applied).
// zt (32KB) is reused as 4 of the 8 wave-buffers after A-frag load.
__global__ __launch_bounds__(256) void k1_mfma(const float* __restrict__ z,
                                               const unsigned short* __restrict__ cbh,
                                               const float* __restrict__ cnorm,
                                               float* __restrict__ out_idx,
                                               int* __restrict__ flagcnt,
                                               int* __restrict__ flaglist) {
    __shared__ __align__(16) char smem[67072];
    float* cand1 = (float*)(smem + 65536);   // [64][2]
    int*   candi = (int*)  (smem + 66048);
    float* cand2 = (float*)(smem + 66560);

    const int tid = threadIdx.x;
    const int lane = tid & 63, wid = tid >> 6;
    const int wx = wid & 1, wy = wid >> 1;
    const int lr = lane & 15, lg = lane >> 4;

    const int n0 = blockIdx.x * 64;
    const int hw0 = n0 & 4095;
    const float* zb = z + (size_t)(n0 >> 12) * (256 * HW);
    const char* cbh_b = (const char*)cbh;

    // ---- stage z tile transposed [row][k] fp16 into smem[0..32768) (swizzled) ----
    {
        const int row = tid & 63, kg8 = tid >> 6;
        const unsigned zswz = (unsigned)((row & 15) << 4);
#pragma unroll
        for (int it = 0; it < 8; ++it) {
            int kb = (kg8 + it * 4) * 8;
            float v[8];
#pragma unroll
            for (int q = 0; q < 8; ++q) v[q] = zb[(size_t)(kb + q) * HW + hw0 + row];
            unsigned pk[4];
#pragma unroll
            for (int q = 0; q < 4; ++q) pk[q] = f16pk(v[2*q], v[2*q+1]);
            unsigned scol = (unsigned)(kb * 2) ^ zswz;
            *(int4*)(smem + row * 512 + scol) = make_int4(pk[0], pk[1], pk[2], pk[3]);
        }
    }
    __syncthreads();

    // ---- A-frags: this wave's 32 rows, full K (64 VGPR) ----
    half8v A[2][8];
#pragma unroll
    for (int mi = 0; mi < 2; ++mi)
#pragma unroll
        for (int ks = 0; ks < 8; ++ks)
            A[mi][ks] = *(const half8v*)(smem + (32*wy + 16*mi + lr) * 512
                                              + ((unsigned)(64*ks + 16*lg) ^ (unsigned)(lr << 4)));
    __syncthreads();   // zt dead; its 32KB becomes wave-buffers below

    // ---- private double buffer for this wave ----
    char* mybuf0 = smem + wid * 8192;            // in old zt area
    char* mybuf1 = smem + 32768 + wid * 8192;
    const int el      = (lane >> 5);             // 0/1: which of the 2 entries per instr
    const unsigned c0 = (unsigned)((lane & 31) * 16);
    const size_t  eb0 = (size_t)wx * 512;        // wave's entry base

    // stage chunk 0
#pragma unroll
    for (int i = 0; i < 8; ++i) {
        int e_loc = 2 * i + el;
        unsigned col = c0 ^ (unsigned)((e_loc & 15) << 4);
        stage16(cbh_b + (eb0 + e_loc) * 512 + col, mybuf0 + i * 1024);
    }

    const float* cnp = cnorm + wx * 512 + lr;
    float b1[8], b2[8]; int bi[8];
#pragma unroll
    for (int i = 0; i < 8; ++i) { b1[i] = 1e30f; b2[i] = 1e30f; bi[i] = 0; }

    for (int c = 0; c < 32; ++c) {
        char* cur = (c & 1) ? mybuf1 : mybuf0;
        if (c < 31) {
            char* nb = (c & 1) ? mybuf0 : mybuf1;
            const size_t ebase = eb0 + (size_t)(c + 1) * 16;
#pragma unroll
            for (int i = 0; i < 8; ++i) {
                int e_loc = 2 * i + el;
                unsigned col = c0 ^ (unsigned)((e_loc & 15) << 4);
                stage16(cbh_b + (ebase + e_loc) * 512 + col, nb + i * 1024);
            }
            asm volatile("s_waitcnt vmcnt(8)" ::: "memory");   // chunk c landed
        } else {
            asm volatile("s_waitcnt vmcnt(0)" ::: "memory");
        }
        __builtin_amdgcn_sched_barrier(0);

        const char* bp = cur + lr * 512;
        float4v a0 = {0.f,0.f,0.f,0.f}, a1 = a0;
#pragma unroll
        for (int ks = 0; ks < 8; ++ks) {
            half8v B = *(const half8v*)(bp + ((unsigned)(64*ks + 16*lg) ^ (unsigned)(lr << 4)));
            a0 = __builtin_amdgcn_mfma_f32_16x16x32_f16(A[0][ks], B, a0, 0, 0, 0);
            a1 = __builtin_amdgcn_mfma_f32_16x16x32_f16(A[1][ks], B, a1, 0, 0, 0);
        }

        // fold (entries strictly ascend with c -> strict < keeps smallest index)
        const float cn = cnp[c * 16];
        const int e = wx * 512 + c * 16 + lr;
#pragma unroll
        for (int r = 0; r < 4; ++r) {
            float s0 = cn - a0[r];
            b2[r] = fminf(b2[r], fmaxf(b1[r], s0));          // med3 clamp idiom
            if (s0 < b1[r]) { b1[r] = s0; bi[r] = e; }
            float s1 = cn - a1[r];
            b2[4+r] = fminf(b2[4+r], fmaxf(b1[4+r], s1));
            if (s1 < b1[4+r]) { b1[4+r] = s1; bi[4+r] = e; }
        }
    }

    // ---- cross-lane argmin over the 16-lane entry dimension (lr) ----
#pragma unroll
    for (int m = 1; m <= 8; m <<= 1) {
#pragma unroll
        for (int s = 0; s < 8; ++s) {
            float o1 = __shfl_xor(b1[s], m, 64);
            float o2 = __shfl_xor(b2[s], m, 64);
            int   oi = __shfl_xor(bi[s], m, 64);
            float m2 = fminf(fmaxf(b1[s], o1), fminf(b2[s], o2));
            if (o1 < b1[s] || (o1 == b1[s] && oi < bi[s])) { b1[s] = o1; bi[s] = oi; }
            b2[s] = m2;
        }
    }
    if (lr == 0) {
#pragma unroll
        for (int mi = 0; mi < 2; ++mi)
#pragma unroll
            for (int r = 0; r < 4; ++r) {
                int row = 32 * wy + 16 * mi + 4 * lg + r;
                cand1[row * 2 + wx] = b1[mi * 4 + r];
                cand2[row * 2 + wx] = b2[mi * 4 + r];
                candi[row * 2 + wx] = bi[mi * 4 + r];
            }
    }
    __syncthreads();
    if (tid < 64) {
        float s1a = cand1[tid * 2], s1b = cand1[tid * 2 + 1];
        int   ia = candi[tid * 2],  ib = candi[tid * 2 + 1];
        float s2 = fminf(fminf(cand2[tid * 2], cand2[tid * 2 + 1]), fmaxf(s1a, s1b));
        float s1; int iw;
        if (s1b < s1a || (s1b == s1a && ib < ia)) { s1 = s1b; iw = ib; }
        else { s1 = s1a; iw = ia; }
        out_idx[n0 + tid] = (float)iw;
        if (s2 - s1 < MARGIN) {
            int p = atomicAdd(flagcnt, 1);
            flaglist[p] = n0 + tid;
        }
    }
}

// ---------------- k1b: exact fp32 re-argmin, 4 rows/block, 4-lane entry groups ----
__global__ __launch_bounds__(256) void k1b_refine(const float* __restrict__ z,
                                                  const float* __restrict__ cb,
                                                  const float* __restrict__ cnorm,
                                                  const int* __restrict__ flagcnt,
                                                  const int* __restrict__ flaglist,
                                                  float* __restrict__ out_idx) {
    __shared__ float zr[4][260];
    __shared__ int   rows[4];
    __shared__ float wb[4][4];
    __shared__ int   wi[4][4];
    const int tid = threadIdx.x;
    const int lane = tid & 63, w = tid >> 6;
    const int gid = tid >> 2, j = tid & 3;     // entry group 0..63, quarter 0..3
    const int count = *flagcnt;
    for (int base = blockIdx.x * 4; base < count; base += gridDim.x * 4) {
        const int nr = min(4, count - base);
        __syncthreads();   // protect zr/rows/wb from previous iteration
        if (tid < nr) rows[tid] = flaglist[base + tid];
        __syncthreads();
        for (int r = 0; r < nr; ++r) {
            const int n = rows[r];
            zr[r][tid] = z[((size_t)(n >> 12) * 256 + tid) * HW + (n & 4095)];
        }
        __syncthreads();

        float acc[16][4];
#pragma unroll
        for (int p = 0; p < 16; ++p)
#pragma unroll
            for (int r = 0; r < 4; ++r) acc[p][r] = 0.f;

        const char* cbase = (const char*)cb + (size_t)gid * 1024 + j * 16;
#pragma unroll 2
        for (int q = 0; q < 16; ++q) {
            float4 zv[4];
#pragma unroll
            for (int r = 0; r < 4; ++r) zv[r] = *(const float4*)(&zr[r][q * 16 + j * 4]);
#pragma unroll
            for (int p = 0; p < 16; ++p) {
                float4 c = *(const float4*)(cbase + (size_t)p * 65536 + q * 64);
#pragma unroll
                for (int r = 0; r < 4; ++r) {
                    float a = acc[p][r];
                    a = fmaf(zv[r].x, c.x, a);
                    a = fmaf(zv[r].y, c.y, a);
                    a = fmaf(zv[r].z, c.z, a);
                    a = fmaf(zv[r].w, c.w, a);
                    acc[p][r] = a;
                }
            }
        }

        float best[4]; int bidx[4];
#pragma unroll
        for (int r = 0; r < 4; ++r) { best[r] = 1e30f; bidx[r] = 0; }
#pragma unroll
        for (int p = 0; p < 16; ++p) {
            const int e = p * 64 + gid;
            const float cn = cnorm[e];
#pragma unroll
            for (int r = 0; r < 4; ++r) {
                float d = acc[p][r];
                d += __shfl_xor(d, 1, 64);
                d += __shfl_xor(d, 2, 64);
                float s = cn - d;
                if (s < best[r]) { best[r] = s; bidx[r] = e; }
            }
        }
#pragma unroll
        for (int m = 1; m <= 32; m <<= 1) {
#pragma unroll
            for (int r = 0; r < 4; ++r) {
                float ob = __shfl_xor(best[r], m, 64);
                int   oi = __shfl_xor(bidx[r], m, 64);
                if (ob < best[r] || (ob == best[r] && oi < bidx[r])) { best[r] = ob; bidx[r] = oi; }
            }
        }
        if (lane == 0) {
#pragma unroll
            for (int r = 0; r < 4; ++r) { wb[w][r] = best[r]; wi[w][r] = bidx[r]; }
        }
        __syncthreads();
        if (tid < nr) {
            float bb = wb[0][tid]; int ii = wi[0][tid];
#pragma unroll
            for (int q = 1; q < 4; ++q)
                if (wb[q][tid] < bb || (wb[q][tid] == bb && wi[q][tid] < ii)) { bb = wb[q][tid]; ii = wi[q][tid]; }
            out_idx[rows[tid]] = (float)ii;
        }
        __syncthreads();
    }
}

// ---------------- k2: LDS-staged gather z_q + fused loss partials ----------------
__global__ __launch_bounds__(256) void k2_scatter(const float* __restrict__ z,
                                                  const float* __restrict__ cb,
                                                  const float* __restrict__ idxf,
                                                  float* __restrict__ zq,
                                                  float* __restrict__ part) {
    __shared__ float cbrow[64][257];
    __shared__ int   earr[64];
    __shared__ float ls[4];
    const int tid = threadIdx.x;
    const int b = blockIdx.x >> 6;
    const int hw0 = (blockIdx.x & 63) * 64;

    if (tid < 64) earr[tid] = (int)idxf[b * 4096 + hw0 + tid];
    __syncthreads();
    {
        const int r = tid >> 2, qd = tid & 3;
        const float4* src = (const float4*)(cb + (size_t)earr[r] * 256 + qd * 64);
#pragma unroll
        for (int i = 0; i < 16; ++i) {
            float4 v = src[i];
            float* d = &cbrow[r][qd * 64 + i * 4];
            d[0] = v.x; d[1] = v.y; d[2] = v.z; d[3] = v.w;
        }
    }
    __syncthreads();

    const int hw = tid & 63, cq = tid >> 6;
    const size_t zbase = ((size_t)b * 256) * 4096 + hw0 + hw;
    float lsum = 0.f;
#pragma unroll 8
    for (int pass = 0; pass < 64; ++pass) {
        const int c = pass * 4 + cq;
        const size_t flat = zbase + (size_t)c * 4096;
        float q = cbrow[hw][c];
        zq[flat] = q;
        float d = q - z[flat];
        lsum = fmaf(d, d, lsum);
    }
#pragma unroll
    for (int m = 32; m >= 1; m >>= 1) lsum += __shfl_down(lsum, m, 64);
    const int lane = tid & 63, w = tid >> 6;
    if (lane == 0) ls[w] = lsum;
    __syncthreads();
    if (tid == 0) part[blockIdx.x] = ls[0] + ls[1] + ls[2] + ls[3];
}

// ---------------- k3: final loss reduce + constants ----------------
__global__ __launch_bounds__(256) void k3_final(const float* __restrict__ part,
                                                float* __restrict__ dout) {
    __shared__ float ls[4];
    float s = 0.f;
#pragma unroll
    for (int it = 0; it < 4; ++it) s += part[threadIdx.x + it * 256];
#pragma unroll
    for (int m = 32; m >= 1; m >>= 1) s += __shfl_down(s, m, 64);
    int lane = threadIdx.x & 63, w = threadIdx.x >> 6;
    if (lane == 0) ls[w] = s;
    __syncthreads();
    if (threadIdx.x == 0) {
        float total = ls[0] + ls[1] + ls[2] + ls[3];
        dout[LOSS_OFF]     = total / 16777216.0f;
        dout[LOSS_OFF + 1] = 0.0f;
    }
}

extern "C" void kernel_launch(void* const* d_in, const int* in_sizes, int n_in,
                              void* d_out, int out_size, void* d_ws, size_t ws_size,
                              hipStream_t stream) {
    const float* z  = (const float*)d_in[0];
    const float* cb = (const float*)d_in[1];
    float* out = (float*)d_out;
    char* ws = (char*)d_ws;

    int*            flagcnt  = (int*)ws;
    int*            flaglist = (int*)(ws + WS_LIST_OFF);
    float*          cnorm    = (float*)(ws + WS_CNORM_OFF);
    unsigned short* cbh      = (unsigned short*)(ws + WS_CBH_OFF);
    float*          part     = (float*)(ws + WS_PART_OFF);

    hipLaunchKernelGGL(k0_prep,   dim3(16),   dim3(256), 0, stream, cb, cnorm, cbh, flagcnt);
    hipLaunchKernelGGL(k1_mfma,   dim3(1024), dim3(256), 0, stream,
                       z, cbh, cnorm, out + IDX_OFF, flagcnt, flaglist);
    hipLaunchKernelGGL(k1b_refine, dim3(2048), dim3(256), 0, stream,
                       z, cb, cnorm, flagcnt, flaglist, out + IDX_OFF);
    hipLaunchKernelGGL(k2_scatter, dim3(1024), dim3(256), 0, stream,
                       z, cb, out + IDX_OFF, out, part);
    hipLaunchKernelGGL(k3_final,  dim3(1),    dim3(256), 0, stream, part, out);
}